// Round 3
// baseline (5992.679 us; speedup 1.0000x reference)
//
#include <hip/hip_runtime.h>

#define D   300
#define D4  75   // D / 4 float4 chunks

// ---------------- embedding: h[n] = atom[x[n,0]] + word[x[n,1]] ----------------
__global__ __launch_bounds__(256) void embed_kernel(const int* __restrict__ x,
                                                    const float4* __restrict__ atomT,
                                                    const float4* __restrict__ wordT,
                                                    float4* __restrict__ h, int N) {
    int idx = blockIdx.x * blockDim.x + threadIdx.x;
    if (idx >= N * D4) return;
    int n = idx / D4, c = idx % D4;
    int a = x[n * 2 + 0];
    int w = x[n * 2 + 1];
    float4 va = atomT[(size_t)a * D4 + c];
    float4 vw = wordT[(size_t)w * D4 + c];
    h[idx] = make_float4(va.x + vw.x, va.y + vw.y, va.z + vw.z, va.w + vw.w);
}

// ---------------- degree / norm ----------------
__global__ __launch_bounds__(256) void deg_init(float* __restrict__ dinv, int N) {
    int i = blockIdx.x * blockDim.x + threadIdx.x;
    if (i < N) dinv[i] = 1.0f;  // self-loop
}
__global__ __launch_bounds__(256) void deg_count(const int* __restrict__ dst, float* __restrict__ dinv, int E) {
    int i = blockIdx.x * blockDim.x + threadIdx.x;
    if (i < E) unsafeAtomicAdd(&dinv[dst[i]], 1.0f);
}
__global__ __launch_bounds__(256) void deg_rsqrt(float* __restrict__ dinv, int N) {
    int i = blockIdx.x * blockDim.x + threadIdx.x;
    if (i < N) dinv[i] = 1.0f / sqrtf(dinv[i]);   // deg >= 1 always (self-loop)
}
__global__ __launch_bounds__(256) void norm_kernel(const int* __restrict__ src, const int* __restrict__ dst,
                                                   const float* __restrict__ dinv, float* __restrict__ nrm, int E) {
    int i = blockIdx.x * blockDim.x + threadIdx.x;
    if (i < E) nrm[i] = dinv[src[i]] * dinv[dst[i]];
}

// ---------------- GEMM: C[M,300] = A[M,300] @ B[300,300] ----------------
// 128x64 tile, 256 threads, 8x4 per thread, BK=20 (300 = 15*20).
__global__ __launch_bounds__(256) void gemm_kernel(const float* __restrict__ A,
                                                   const float* __restrict__ B,
                                                   float* __restrict__ C, int M) {
    __shared__ float As[128][21];  // +1 pad: inner reads conflict-free
    __shared__ float Bs[20][65];
    const int bm = blockIdx.x * 128;
    const int bn = blockIdx.y * 64;
    const int tid = threadIdx.x;
    const int tx = tid & 15;   // n dir, 4 cols each
    const int ty = tid >> 4;   // m dir, 8 rows each
    float acc[8][4] = {};

    for (int k0 = 0; k0 < D; k0 += 20) {
        #pragma unroll
        for (int i = 0; i < 10; ++i) {               // 128*20 = 2560 = 10*256
            int t = tid + i * 256;
            int r = t / 20, c = t % 20;
            int gr = bm + r;
            As[r][c] = (gr < M) ? A[(size_t)gr * D + k0 + c] : 0.f;
        }
        #pragma unroll
        for (int i = 0; i < 5; ++i) {                // 20*64 = 1280 = 5*256
            int t = tid + i * 256;
            int r = t >> 6, c = t & 63;
            int gc = bn + c;
            Bs[r][c] = (gc < D) ? B[(size_t)(k0 + r) * D + gc] : 0.f;
        }
        __syncthreads();
        #pragma unroll
        for (int k = 0; k < 20; ++k) {
            float a[8], bv[4];
            #pragma unroll
            for (int i = 0; i < 8; ++i) a[i] = As[ty * 8 + i][k];
            #pragma unroll
            for (int j = 0; j < 4; ++j) bv[j] = Bs[k][tx * 4 + j];
            #pragma unroll
            for (int i = 0; i < 8; ++i)
                #pragma unroll
                for (int j = 0; j < 4; ++j)
                    acc[i][j] = fmaf(a[i], bv[j], acc[i][j]);
        }
        __syncthreads();
    }
    #pragma unroll
    for (int i = 0; i < 8; ++i) {
        int gr = bm + ty * 8 + i;
        if (gr >= M) break;
        int gc = bn + tx * 4;
        if (gc + 3 < D) {   // gr*300 + gc is 16B aligned (300%4==0, gc%4==0)
            *(float4*)&C[(size_t)gr * D + gc] = make_float4(acc[i][0], acc[i][1], acc[i][2], acc[i][3]);
        } else {
            #pragma unroll
            for (int j = 0; j < 4; ++j)
                if (gc + j < D) C[(size_t)gr * D + gc + j] = acc[i][j];
        }
    }
}

// ---------------- hop: h_new = b + hl * dinv^2 (self loop), then edge scatter ----------------
__global__ __launch_bounds__(256) void selfinit_kernel(const float4* __restrict__ hl,
                                                       const float* __restrict__ dinv,
                                                       const float4* __restrict__ bias4,
                                                       float4* __restrict__ hnew, int N) {
    int idx = blockIdx.x * blockDim.x + threadIdx.x;
    if (idx >= N * D4) return;
    int n = idx / D4, c = idx % D4;
    float s = dinv[n]; s = s * s;
    float4 v = hl[idx];
    float4 b = bias4[c];
    hnew[idx] = make_float4(b.x + v.x * s, b.y + v.y * s, b.z + v.z * s, b.w + v.w * s);
}

__global__ __launch_bounds__(256) void scatter_kernel(const float4* __restrict__ hl,
                                                      const int* __restrict__ src,
                                                      const int* __restrict__ dst,
                                                      const float* __restrict__ nrm,
                                                      float* __restrict__ hnew, int E) {
    int idx = blockIdx.x * blockDim.x + threadIdx.x;
    if (idx >= E * D4) return;
    int e = idx / D4, c = idx % D4;
    float nm = nrm[e];
    float4 v = hl[(size_t)src[e] * D4 + c];
    float* p = hnew + (size_t)dst[e] * D + c * 4;
    unsafeAtomicAdd(p + 0, v.x * nm);
    unsafeAtomicAdd(p + 1, v.y * nm);
    unsafeAtomicAdd(p + 2, v.z * nm);
    unsafeAtomicAdd(p + 3, v.w * nm);
}

// ---------------- pooling ----------------
__global__ __launch_bounds__(256) void pool_sum(const float4* __restrict__ h,
                                                const int* __restrict__ batch,
                                                float* __restrict__ out, int N) {
    int idx = blockIdx.x * blockDim.x + threadIdx.x;
    if (idx >= N * D4) return;
    int n = idx / D4, c = idx % D4;
    int g = batch[n];
    float4 v = h[idx];
    float* p = out + (size_t)g * D + c * 4;
    unsafeAtomicAdd(p + 0, v.x);
    unsafeAtomicAdd(p + 1, v.y);
    unsafeAtomicAdd(p + 2, v.z);
    unsafeAtomicAdd(p + 3, v.w);
}
__global__ __launch_bounds__(256) void count_kernel(const int* __restrict__ batch, float* __restrict__ counts, int N) {
    int i = blockIdx.x * blockDim.x + threadIdx.x;
    if (i < N) unsafeAtomicAdd(&counts[batch[i]], 1.0f);
}
__global__ __launch_bounds__(256) void divide_kernel(float* __restrict__ out, const float* __restrict__ counts, int G) {
    int i = blockIdx.x * blockDim.x + threadIdx.x;
    if (i < G * D) out[i] /= fmaxf(counts[i / D], 1.0f);
}

extern "C" void kernel_launch(void* const* d_in, const int* in_sizes, int n_in,
                              void* d_out, int out_size, void* d_ws, size_t ws_size,
                              hipStream_t stream) {
    (void)n_in; (void)ws_size;
    const int*   x     = (const int*)d_in[0];
    const int*   ei    = (const int*)d_in[1];
    const int*   batch = (const int*)d_in[2];
    // d_in[3] = num_hops scalar on device; fixed at 4 for this problem.
    const float* atomT = (const float*)d_in[4];
    const float* wordT = (const float*)d_in[5];
    const float* W     = (const float*)d_in[6];
    const float* bias  = (const float*)d_in[7];

    const int N = in_sizes[0] / 2;
    const int E = in_sizes[1] / 2;
    const int G = out_size / D;
    const int NUM_HOPS = 4;

    const int* src = ei;
    const int* dst = ei + E;

    float* h      = (float*)d_ws;                  // N*300
    float* hl     = h + (size_t)N * D;             // N*300
    float* dinv   = hl + (size_t)N * D;            // N
    float* nrm    = dinv + N;                      // E
    float* counts = nrm + E;                       // G

    const int B = 256;
    int ndBlocks = (N * D4 + B - 1) / B;
    int edBlocks = (E * D4 + B - 1) / B;

    embed_kernel<<<ndBlocks, B, 0, stream>>>(x, (const float4*)atomT, (const float4*)wordT, (float4*)h, N);
    deg_init  <<<(N + B - 1) / B, B, 0, stream>>>(dinv, N);
    deg_count <<<(E + B - 1) / B, B, 0, stream>>>(dst, dinv, E);
    deg_rsqrt <<<(N + B - 1) / B, B, 0, stream>>>(dinv, N);
    norm_kernel<<<(E + B - 1) / B, B, 0, stream>>>(src, dst, dinv, nrm, E);

    dim3 ggrid((N + 127) / 128, (D + 63) / 64);
    for (int hop = 0; hop < NUM_HOPS; ++hop) {
        gemm_kernel   <<<ggrid, 256, 0, stream>>>(h, W, hl, N);
        selfinit_kernel<<<ndBlocks, B, 0, stream>>>((const float4*)hl, dinv, (const float4*)bias, (float4*)h, N);
        scatter_kernel <<<edBlocks, B, 0, stream>>>((const float4*)hl, src, dst, nrm, h, E);
    }

    hipMemsetAsync(d_out, 0, (size_t)out_size * sizeof(float), stream);
    hipMemsetAsync(counts, 0, (size_t)G * sizeof(float), stream);
    pool_sum    <<<ndBlocks, B, 0, stream>>>((const float4*)h, batch, (float*)d_out, N);
    count_kernel<<<(N + B - 1) / B, B, 0, stream>>>(batch, counts, N);
    divide_kernel<<<(G * D + B - 1) / B, B, 0, stream>>>((float*)d_out, counts, G);
}

// Round 4
// 1945.806 us; speedup vs baseline: 3.0798x; 3.0798x over previous
//
#include <hip/hip_runtime.h>

#define D   300
#define D4  75   // D / 4 float4 chunks

// ---------------- embedding: h[n] = atom[x[n,0]] + word[x[n,1]] ----------------
__global__ __launch_bounds__(256) void embed_kernel(const int* __restrict__ x,
                                                    const float4* __restrict__ atomT,
                                                    const float4* __restrict__ wordT,
                                                    float4* __restrict__ h, int N) {
    int idx = blockIdx.x * blockDim.x + threadIdx.x;
    if (idx >= N * D4) return;
    int n = idx / D4, c = idx % D4;
    int a = x[n * 2 + 0];
    int w = x[n * 2 + 1];
    float4 va = atomT[(size_t)a * D4 + c];
    float4 vw = wordT[(size_t)w * D4 + c];
    h[idx] = make_float4(va.x + vw.x, va.y + vw.y, va.z + vw.z, va.w + vw.w);
}

// ---------------- CSR build ----------------
__global__ __launch_bounds__(256) void cnt_kernel(const int* __restrict__ dst, int* __restrict__ cnt, int E) {
    int i = blockIdx.x * blockDim.x + threadIdx.x;
    if (i < E) atomicAdd(&cnt[dst[i]], 1);
}
__global__ __launch_bounds__(256) void dinv_kernel(const int* __restrict__ cnt, float* __restrict__ dinv, int N) {
    int i = blockIdx.x * blockDim.x + threadIdx.x;
    if (i < N) dinv[i] = rsqrtf((float)(cnt[i] + 1));   // +1 self-loop; deg >= 1 always
}
// single-workgroup exclusive scan of cnt[0..N) -> off, cursor; off[N] = total
__global__ __launch_bounds__(1024) void scan_kernel(const int* __restrict__ cnt,
                                                    int* __restrict__ off, int* __restrict__ cursor, int N) {
    __shared__ int warp_sums[16];
    __shared__ int chunk_base;
    const int tid = threadIdx.x;
    const int lane = tid & 63;
    const int wid = tid >> 6;
    if (tid == 0) chunk_base = 0;
    __syncthreads();
    for (int base = 0; base < N; base += 1024) {
        int i = base + tid;
        int v = (i < N) ? cnt[i] : 0;
        int s = v;                                  // inclusive scan within wave
        #pragma unroll
        for (int d = 1; d < 64; d <<= 1) {
            int t = __shfl_up(s, d, 64);
            if (lane >= d) s += t;
        }
        if (lane == 63) warp_sums[wid] = s;
        __syncthreads();
        if (wid == 0) {                             // scan the 16 wave sums
            int ws = (lane < 16) ? warp_sums[lane] : 0;
            #pragma unroll
            for (int d = 1; d < 16; d <<= 1) {
                int t = __shfl_up(ws, d, 64);
                if (lane >= d) ws += t;
            }
            if (lane < 16) warp_sums[lane] = ws;
        }
        __syncthreads();
        int excl = chunk_base + (wid ? warp_sums[wid - 1] : 0) + s - v;
        if (i < N) { off[i] = excl; cursor[i] = excl; }
        int total = warp_sums[15];
        __syncthreads();                            // all reads of chunk_base/warp_sums done
        if (tid == 0) chunk_base += total;
        __syncthreads();
    }
    if (tid == 0) off[N] = chunk_base;
}
__global__ __launch_bounds__(256) void fill_kernel(const int* __restrict__ src, const int* __restrict__ dst,
                                                   const float* __restrict__ dinv, int* __restrict__ cursor,
                                                   int* __restrict__ csr_src, float* __restrict__ csr_w, int E) {
    int e = blockIdx.x * blockDim.x + threadIdx.x;
    if (e >= E) return;
    int s = src[e], d = dst[e];
    int slot = atomicAdd(&cursor[d], 1);
    csr_src[slot] = s;
    csr_w[slot] = dinv[s] * dinv[d];
}

// ---------------- GEMM: C[M,300] = A[M,300] @ B[300,300] ----------------
// 128x64 tile, 256 threads, 8x4 per thread, BK=20 (300 = 15*20).
__global__ __launch_bounds__(256) void gemm_kernel(const float* __restrict__ A,
                                                   const float* __restrict__ B,
                                                   float* __restrict__ C, int M) {
    __shared__ float As[128][21];  // +1 pad: inner reads conflict-free
    __shared__ float Bs[20][65];
    const int bm = blockIdx.x * 128;
    const int bn = blockIdx.y * 64;
    const int tid = threadIdx.x;
    const int tx = tid & 15;   // n dir, 4 cols each
    const int ty = tid >> 4;   // m dir, 8 rows each
    float acc[8][4] = {};

    for (int k0 = 0; k0 < D; k0 += 20) {
        #pragma unroll
        for (int i = 0; i < 10; ++i) {               // 128*20 = 2560 = 10*256
            int t = tid + i * 256;
            int r = t / 20, c = t % 20;
            int gr = bm + r;
            As[r][c] = (gr < M) ? A[(size_t)gr * D + k0 + c] : 0.f;
        }
        #pragma unroll
        for (int i = 0; i < 5; ++i) {                // 20*64 = 1280 = 5*256
            int t = tid + i * 256;
            int r = t >> 6, c = t & 63;
            int gc = bn + c;
            Bs[r][c] = (gc < D) ? B[(size_t)(k0 + r) * D + gc] : 0.f;
        }
        __syncthreads();
        #pragma unroll
        for (int k = 0; k < 20; ++k) {
            float a[8], bv[4];
            #pragma unroll
            for (int i = 0; i < 8; ++i) a[i] = As[ty * 8 + i][k];
            #pragma unroll
            for (int j = 0; j < 4; ++j) bv[j] = Bs[k][tx * 4 + j];
            #pragma unroll
            for (int i = 0; i < 8; ++i)
                #pragma unroll
                for (int j = 0; j < 4; ++j)
                    acc[i][j] = fmaf(a[i], bv[j], acc[i][j]);
        }
        __syncthreads();
    }
    #pragma unroll
    for (int i = 0; i < 8; ++i) {
        int gr = bm + ty * 8 + i;
        if (gr >= M) break;
        int gc = bn + tx * 4;
        if (gc + 3 < D) {
            *(float4*)&C[(size_t)gr * D + gc] = make_float4(acc[i][0], acc[i][1], acc[i][2], acc[i][3]);
        } else {
            #pragma unroll
            for (int j = 0; j < 4; ++j)
                if (gc + j < D) C[(size_t)gr * D + gc + j] = acc[i][j];
        }
    }
}

// ---------------- hop aggregate (replaces selfinit + scatter, no atomics) ----------------
// h[n,c] = b[c] + hl[n,c]*dinv[n]^2 + sum_{j in in(n)} hl[csr_src[j],c] * csr_w[j]
__global__ __launch_bounds__(256) void gather_kernel(const float4* __restrict__ hl,
                                                     const int* __restrict__ off,
                                                     const int* __restrict__ csr_src,
                                                     const float* __restrict__ csr_w,
                                                     const float* __restrict__ dinv,
                                                     const float4* __restrict__ bias4,
                                                     float4* __restrict__ h, int N) {
    int idx = blockIdx.x * blockDim.x + threadIdx.x;
    if (idx >= N * D4) return;
    int n = idx / D4, c = idx - n * D4;
    float s = dinv[n]; s = s * s;
    float4 v = hl[idx];
    float4 bb = bias4[c];
    float4 acc = make_float4(bb.x + v.x * s, bb.y + v.y * s, bb.z + v.z * s, bb.w + v.w * s);
    int j0 = off[n], j1 = off[n + 1];
    for (int j = j0; j < j1; ++j) {
        int sn = csr_src[j];               // wave-uniform for full-node waves -> broadcast
        float w = csr_w[j];
        float4 u = hl[(size_t)sn * D4 + c];
        acc.x += u.x * w; acc.y += u.y * w; acc.z += u.z * w; acc.w += u.w * w;
    }
    h[idx] = acc;
}

// ---------------- pooling ----------------
__global__ __launch_bounds__(256) void pool_sum(const float4* __restrict__ h,
                                                const int* __restrict__ batch,
                                                float* __restrict__ out, int N) {
    int idx = blockIdx.x * blockDim.x + threadIdx.x;
    if (idx >= N * D4) return;
    int n = idx / D4, c = idx % D4;
    int g = batch[n];
    float4 v = h[idx];
    float* p = out + (size_t)g * D + c * 4;
    unsafeAtomicAdd(p + 0, v.x);
    unsafeAtomicAdd(p + 1, v.y);
    unsafeAtomicAdd(p + 2, v.z);
    unsafeAtomicAdd(p + 3, v.w);
}
__global__ __launch_bounds__(256) void count_kernel(const int* __restrict__ batch, float* __restrict__ counts, int N) {
    int i = blockIdx.x * blockDim.x + threadIdx.x;
    if (i < N) unsafeAtomicAdd(&counts[batch[i]], 1.0f);
}
__global__ __launch_bounds__(256) void divide_kernel(float* __restrict__ out, const float* __restrict__ counts, int G) {
    int i = blockIdx.x * blockDim.x + threadIdx.x;
    if (i < G * D) out[i] /= fmaxf(counts[i / D], 1.0f);
}

extern "C" void kernel_launch(void* const* d_in, const int* in_sizes, int n_in,
                              void* d_out, int out_size, void* d_ws, size_t ws_size,
                              hipStream_t stream) {
    (void)n_in; (void)ws_size;
    const int*   x     = (const int*)d_in[0];
    const int*   ei    = (const int*)d_in[1];
    const int*   batch = (const int*)d_in[2];
    // d_in[3] = num_hops scalar on device; fixed at 4 for this problem.
    const float* atomT = (const float*)d_in[4];
    const float* wordT = (const float*)d_in[5];
    const float* W     = (const float*)d_in[6];
    const float* bias  = (const float*)d_in[7];

    const int N = in_sizes[0] / 2;
    const int E = in_sizes[1] / 2;
    const int G = out_size / D;
    const int NUM_HOPS = 4;

    const int* src = ei;
    const int* dst = ei + E;

    // workspace layout (floats unless noted)
    float* h       = (float*)d_ws;                   // N*300
    float* hl      = h + (size_t)N * D;              // N*300
    float* dinv    = hl + (size_t)N * D;             // N
    float* csr_w   = dinv + N;                       // E
    float* counts  = csr_w + E;                      // G
    int*   cnt     = (int*)(counts + G);             // N
    int*   off     = cnt + N;                        // N+1
    int*   cursor  = off + N + 1;                    // N
    int*   csr_src = cursor + N;                     // E

    const int B = 256;
    int ndBlocks = (N * D4 + B - 1) / B;

    embed_kernel<<<ndBlocks, B, 0, stream>>>(x, (const float4*)atomT, (const float4*)wordT, (float4*)h, N);

    // CSR build
    hipMemsetAsync(cnt, 0, (size_t)N * sizeof(int), stream);
    cnt_kernel <<<(E + B - 1) / B, B, 0, stream>>>(dst, cnt, E);
    dinv_kernel<<<(N + B - 1) / B, B, 0, stream>>>(cnt, dinv, N);
    scan_kernel<<<1, 1024, 0, stream>>>(cnt, off, cursor, N);
    fill_kernel<<<(E + B - 1) / B, B, 0, stream>>>(src, dst, dinv, cursor, csr_src, csr_w, E);

    dim3 ggrid((N + 127) / 128, (D + 63) / 64);
    for (int hop = 0; hop < NUM_HOPS; ++hop) {
        gemm_kernel  <<<ggrid, 256, 0, stream>>>(h, W, hl, N);
        gather_kernel<<<ndBlocks, B, 0, stream>>>((const float4*)hl, off, csr_src, csr_w, dinv,
                                                  (const float4*)bias, (float4*)h, N);
    }

    hipMemsetAsync(d_out, 0, (size_t)out_size * sizeof(float), stream);
    hipMemsetAsync(counts, 0, (size_t)G * sizeof(float), stream);
    pool_sum    <<<ndBlocks, B, 0, stream>>>((const float4*)h, batch, (float*)d_out, N);
    count_kernel<<<(N + B - 1) / B, B, 0, stream>>>(batch, counts, N);
    divide_kernel<<<(G * D + B - 1) / B, B, 0, stream>>>((float*)d_out, counts, G);
}

// Round 5
// 1044.121 us; speedup vs baseline: 5.7394x; 1.8636x over previous
//
#include <hip/hip_runtime.h>

#define D    300
#define D4   75    // D / 4 float4 chunks
#define KPAD 320   // K padded to 10 MFMA k-steps of 32
#define BM   128
#define BN   64
#define BK   64
#define LDT  72    // LDS row stride in bf16 units (144 B: 16B-aligned, bank-spread)

typedef short bf16x8 __attribute__((ext_vector_type(8)));
typedef float f32x4  __attribute__((ext_vector_type(4)));

__device__ inline short f2bh(float f) {           // fp32 -> bf16 RNE (bit trick)
    unsigned u = __float_as_uint(f);
    unsigned r = (u + 0x7FFFu + ((u >> 16) & 1u)) >> 16;
    return (short)r;
}
__device__ inline float bh2f(short s) {
    return __uint_as_float(((unsigned)(unsigned short)s) << 16);
}

// ---------------- embedding ----------------
__global__ __launch_bounds__(256) void embed_kernel(const int* __restrict__ x,
                                                    const float4* __restrict__ atomT,
                                                    const float4* __restrict__ wordT,
                                                    float4* __restrict__ h, int N) {
    int idx = blockIdx.x * blockDim.x + threadIdx.x;
    if (idx >= N * D4) return;
    int n = idx / D4, c = idx % D4;
    int a = x[n * 2 + 0];
    int w = x[n * 2 + 1];
    float4 va = atomT[(size_t)a * D4 + c];
    float4 vw = wordT[(size_t)w * D4 + c];
    h[idx] = make_float4(va.x + vw.x, va.y + vw.y, va.z + vw.z, va.w + vw.w);
}

// ---------------- W -> transposed, k-padded, split-bf16 pair ----------------
__global__ __launch_bounds__(256) void wprep_kernel(const float* __restrict__ W,
                                                    short* __restrict__ wh, short* __restrict__ wl) {
    int id = blockIdx.x * blockDim.x + threadIdx.x;
    if (id >= D * KPAD) return;
    int n = id / KPAD, k = id % KPAD;
    float v = (k < D) ? W[(size_t)k * D + n] : 0.f;
    short hh = f2bh(v);
    short ll = f2bh(v - bh2f(hh));
    wh[id] = hh; wl[id] = ll;
}

// ---------------- CSR build ----------------
__global__ __launch_bounds__(256) void cnt_kernel(const int* __restrict__ dst, int* __restrict__ cnt, int E) {
    int i = blockIdx.x * blockDim.x + threadIdx.x;
    if (i < E) atomicAdd(&cnt[dst[i]], 1);
}
__global__ __launch_bounds__(256) void dinv_kernel(const int* __restrict__ cnt, float* __restrict__ dinv, int N) {
    int i = blockIdx.x * blockDim.x + threadIdx.x;
    if (i < N) dinv[i] = rsqrtf((float)(cnt[i] + 1));   // +1 self-loop
}
__global__ __launch_bounds__(1024) void scan_kernel(const int* __restrict__ cnt,
                                                    int* __restrict__ off, int* __restrict__ cursor, int N) {
    __shared__ int warp_sums[16];
    __shared__ int chunk_base;
    const int tid = threadIdx.x;
    const int lane = tid & 63;
    const int wid = tid >> 6;
    if (tid == 0) chunk_base = 0;
    __syncthreads();
    for (int base = 0; base < N; base += 1024) {
        int i = base + tid;
        int v = (i < N) ? cnt[i] : 0;
        int s = v;
        #pragma unroll
        for (int d = 1; d < 64; d <<= 1) {
            int t = __shfl_up(s, d, 64);
            if (lane >= d) s += t;
        }
        if (lane == 63) warp_sums[wid] = s;
        __syncthreads();
        if (wid == 0) {
            int ws = (lane < 16) ? warp_sums[lane] : 0;
            #pragma unroll
            for (int d = 1; d < 16; d <<= 1) {
                int t = __shfl_up(ws, d, 64);
                if (lane >= d) ws += t;
            }
            if (lane < 16) warp_sums[lane] = ws;
        }
        __syncthreads();
        int excl = chunk_base + (wid ? warp_sums[wid - 1] : 0) + s - v;
        if (i < N) { off[i] = excl; cursor[i] = excl; }
        int total = warp_sums[15];
        __syncthreads();
        if (tid == 0) chunk_base += total;
        __syncthreads();
    }
    if (tid == 0) off[N] = chunk_base;
}
__global__ __launch_bounds__(256) void fill_kernel(const int* __restrict__ src, const int* __restrict__ dst,
                                                   const float* __restrict__ dinv, int* __restrict__ cursor,
                                                   int* __restrict__ csr_src, float* __restrict__ csr_w, int E) {
    int e = blockIdx.x * blockDim.x + threadIdx.x;
    if (e >= E) return;
    int s = src[e], d = dst[e];
    int slot = atomicAdd(&cursor[d], 1);
    csr_src[slot] = s;
    csr_w[slot] = dinv[s] * dinv[d];
}

// ---------------- GEMM via MFMA, split-bf16: C = A @ W ----------------
// A fp32 [M][300] (converted+split on the fly), Wt pre-split bf16 [300][KPAD] (B^T layout).
// Logical k placed identically in A/B fragments -> contraction is k-permutation-invariant.
__global__ __launch_bounds__(256) void gemm_mfma(const float* __restrict__ A,
                                                 const short* __restrict__ WtH,
                                                 const short* __restrict__ WtL,
                                                 float* __restrict__ C, int M) {
    __shared__ short AsH[BM][LDT], AsL[BM][LDT];
    __shared__ short BsH[BN][LDT], BsL[BN][LDT];

    const int tid = threadIdx.x;
    const int bm = blockIdx.x * BM;
    const int n0 = blockIdx.y * BN;
    const int lane = tid & 63, wid = tid >> 6;
    const int g4 = lane >> 4, l16 = lane & 15;
    const int wr0 = wid * 32;

    f32x4 acc[2][4];
    #pragma unroll
    for (int i = 0; i < 2; ++i)
        #pragma unroll
        for (int j = 0; j < 4; ++j) acc[i][j] = (f32x4)0.0f;

    for (int k0 = 0; k0 < KPAD; k0 += BK) {
        // ---- stage A: 128x64 fp32 -> split bf16 pair ----
        #pragma unroll
        for (int i = 0; i < 8; ++i) {
            int g = tid + i * 256;            // 2048 float4 granules
            int r = g >> 4, k = (g & 15) * 4;
            int gr = bm + r;
            float4 v = make_float4(0.f, 0.f, 0.f, 0.f);
            if (gr < M) {
                int gk = k0 + k;
                if (gk + 3 < D) v = *(const float4*)&A[(size_t)gr * D + gk];
                else {
                    float t0 = (gk + 0 < D) ? A[(size_t)gr * D + gk + 0] : 0.f;
                    float t1 = (gk + 1 < D) ? A[(size_t)gr * D + gk + 1] : 0.f;
                    float t2 = (gk + 2 < D) ? A[(size_t)gr * D + gk + 2] : 0.f;
                    float t3 = (gk + 3 < D) ? A[(size_t)gr * D + gk + 3] : 0.f;
                    v = make_float4(t0, t1, t2, t3);
                }
            }
            short4 hh, ll;
            hh.x = f2bh(v.x); ll.x = f2bh(v.x - bh2f(hh.x));
            hh.y = f2bh(v.y); ll.y = f2bh(v.y - bh2f(hh.y));
            hh.z = f2bh(v.z); ll.z = f2bh(v.z - bh2f(hh.z));
            hh.w = f2bh(v.w); ll.w = f2bh(v.w - bh2f(hh.w));
            *(short4*)&AsH[r][k] = hh;
            *(short4*)&AsL[r][k] = ll;
        }
        // ---- stage B: 64x64 bf16 pair, straight 16B copies ----
        #pragma unroll
        for (int i = 0; i < 2; ++i) {
            int g = tid + i * 256;            // 512 chunks of 8 bf16
            int r = g >> 3, k = (g & 7) * 8;
            int gn = n0 + r;
            bf16x8 vh = (bf16x8)(short)0, vl = (bf16x8)(short)0;
            if (gn < D) {
                vh = *(const bf16x8*)&WtH[(size_t)gn * KPAD + k0 + k];
                vl = *(const bf16x8*)&WtL[(size_t)gn * KPAD + k0 + k];
            }
            *(bf16x8*)&BsH[r][k] = vh;
            *(bf16x8*)&BsL[r][k] = vl;
        }
        __syncthreads();

        #pragma unroll
        for (int s = 0; s < 2; ++s) {         // two K=32 steps per BK=64
            bf16x8 ah[2], al[2], bh[4], bl[4];
            #pragma unroll
            for (int mf = 0; mf < 2; ++mf) {
                int row = wr0 + mf * 16 + l16;
                ah[mf] = *(const bf16x8*)&AsH[row][s * 32 + g4 * 8];
                al[mf] = *(const bf16x8*)&AsL[row][s * 32 + g4 * 8];
            }
            #pragma unroll
            for (int nf = 0; nf < 4; ++nf) {
                int col = nf * 16 + l16;
                bh[nf] = *(const bf16x8*)&BsH[col][s * 32 + g4 * 8];
                bl[nf] = *(const bf16x8*)&BsL[col][s * 32 + g4 * 8];
            }
            #pragma unroll
            for (int mf = 0; mf < 2; ++mf)
                #pragma unroll
                for (int nf = 0; nf < 4; ++nf) {
                    acc[mf][nf] = __builtin_amdgcn_mfma_f32_16x16x32_bf16(ah[mf], bh[nf], acc[mf][nf], 0, 0, 0);
                    acc[mf][nf] = __builtin_amdgcn_mfma_f32_16x16x32_bf16(ah[mf], bl[nf], acc[mf][nf], 0, 0, 0);
                    acc[mf][nf] = __builtin_amdgcn_mfma_f32_16x16x32_bf16(al[mf], bh[nf], acc[mf][nf], 0, 0, 0);
                }
        }
        __syncthreads();
    }

    // ---- C write: row=(lane>>4)*4+reg, col=lane&15 per 16x16 frag [m89-verified] ----
    #pragma unroll
    for (int mf = 0; mf < 2; ++mf)
        #pragma unroll
        for (int nf = 0; nf < 4; ++nf)
            #pragma unroll
            for (int reg = 0; reg < 4; ++reg) {
                int grow = bm + wr0 + mf * 16 + g4 * 4 + reg;
                int gcol = n0 + nf * 16 + l16;
                if (grow < M && gcol < D)
                    C[(size_t)grow * D + gcol] = acc[mf][nf][reg];
            }
}

// ---------------- hop aggregate (gather, no atomics) ----------------
__global__ __launch_bounds__(256) void gather_kernel(const float4* __restrict__ hl,
                                                     const int* __restrict__ off,
                                                     const int* __restrict__ csr_src,
                                                     const float* __restrict__ csr_w,
                                                     const float* __restrict__ dinv,
                                                     const float4* __restrict__ bias4,
                                                     float4* __restrict__ h, int N) {
    int idx = blockIdx.x * blockDim.x + threadIdx.x;
    if (idx >= N * D4) return;
    int n = idx / D4, c = idx - n * D4;
    float s = dinv[n]; s = s * s;
    float4 v = hl[idx];
    float4 bb = bias4[c];
    float4 acc = make_float4(bb.x + v.x * s, bb.y + v.y * s, bb.z + v.z * s, bb.w + v.w * s);
    int j0 = off[n], j1 = off[n + 1];
    for (int j = j0; j < j1; ++j) {
        int sn = csr_src[j];
        float w = csr_w[j];
        float4 u = hl[(size_t)sn * D4 + c];
        acc.x += u.x * w; acc.y += u.y * w; acc.z += u.z * w; acc.w += u.w * w;
    }
    h[idx] = acc;
}

// ---------------- pooling ----------------
__global__ __launch_bounds__(256) void pool_sum(const float4* __restrict__ h,
                                                const int* __restrict__ batch,
                                                float* __restrict__ out, int N) {
    int idx = blockIdx.x * blockDim.x + threadIdx.x;
    if (idx >= N * D4) return;
    int n = idx / D4, c = idx % D4;
    int g = batch[n];
    float4 v = h[idx];
    float* p = out + (size_t)g * D + c * 4;
    unsafeAtomicAdd(p + 0, v.x);
    unsafeAtomicAdd(p + 1, v.y);
    unsafeAtomicAdd(p + 2, v.z);
    unsafeAtomicAdd(p + 3, v.w);
}
__global__ __launch_bounds__(256) void count_kernel(const int* __restrict__ batch, float* __restrict__ counts, int N) {
    int i = blockIdx.x * blockDim.x + threadIdx.x;
    if (i < N) unsafeAtomicAdd(&counts[batch[i]], 1.0f);
}
__global__ __launch_bounds__(256) void divide_kernel(float* __restrict__ out, const float* __restrict__ counts, int G) {
    int i = blockIdx.x * blockDim.x + threadIdx.x;
    if (i < G * D) out[i] /= fmaxf(counts[i / D], 1.0f);
}

extern "C" void kernel_launch(void* const* d_in, const int* in_sizes, int n_in,
                              void* d_out, int out_size, void* d_ws, size_t ws_size,
                              hipStream_t stream) {
    (void)n_in; (void)ws_size;
    const int*   x     = (const int*)d_in[0];
    const int*   ei    = (const int*)d_in[1];
    const int*   batch = (const int*)d_in[2];
    // d_in[3] = num_hops (fixed 4)
    const float* atomT = (const float*)d_in[4];
    const float* wordT = (const float*)d_in[5];
    const float* W     = (const float*)d_in[6];
    const float* bias  = (const float*)d_in[7];

    const int N = in_sizes[0] / 2;
    const int E = in_sizes[1] / 2;
    const int G = out_size / D;
    const int NUM_HOPS = 4;

    const int* src = ei;
    const int* dst = ei + E;

    // workspace layout
    float* h       = (float*)d_ws;                    // N*300 f32
    float* hl      = h + (size_t)N * D;               // N*300 f32
    float* dinv    = hl + (size_t)N * D;              // N
    float* csr_w   = dinv + N;                        // E
    float* counts  = csr_w + E;                       // G
    short* wtH     = (short*)(counts + G);            // 300*KPAD bf16
    short* wtL     = wtH + (size_t)D * KPAD;          // 300*KPAD bf16
    int*   cnt     = (int*)(wtL + (size_t)D * KPAD);  // N
    int*   off     = cnt + N;                         // N+1
    int*   cursor  = off + N + 1;                     // N
    int*   csr_src = cursor + N;                      // E

    const int B = 256;
    int ndBlocks = (N * D4 + B - 1) / B;

    embed_kernel<<<ndBlocks, B, 0, stream>>>(x, (const float4*)atomT, (const float4*)wordT, (float4*)h, N);
    wprep_kernel<<<(D * KPAD + B - 1) / B, B, 0, stream>>>(W, wtH, wtL);

    hipMemsetAsync(cnt, 0, (size_t)N * sizeof(int), stream);
    cnt_kernel <<<(E + B - 1) / B, B, 0, stream>>>(dst, cnt, E);
    dinv_kernel<<<(N + B - 1) / B, B, 0, stream>>>(cnt, dinv, N);
    scan_kernel<<<1, 1024, 0, stream>>>(cnt, off, cursor, N);
    fill_kernel<<<(E + B - 1) / B, B, 0, stream>>>(src, dst, dinv, cursor, csr_src, csr_w, E);

    dim3 ggrid((N + BM - 1) / BM, (D + BN - 1) / BN);
    for (int hop = 0; hop < NUM_HOPS; ++hop) {
        gemm_mfma    <<<ggrid, 256, 0, stream>>>(h, wtH, wtL, hl, N);
        gather_kernel<<<ndBlocks, B, 0, stream>>>((const float4*)hl, off, csr_src, csr_w, dinv,
                                                  (const float4*)bias, (float4*)h, N);
    }

    hipMemsetAsync(d_out, 0, (size_t)out_size * sizeof(float), stream);
    hipMemsetAsync(counts, 0, (size_t)G * sizeof(float), stream);
    pool_sum    <<<ndBlocks, B, 0, stream>>>((const float4*)h, batch, (float*)d_out, N);
    count_kernel<<<(N + B - 1) / B, B, 0, stream>>>(batch, counts, N);
    divide_kernel<<<(G * D + B - 1) / B, B, 0, stream>>>((float*)d_out, counts, G);
}

// Round 6
// 826.575 us; speedup vs baseline: 7.2500x; 1.2632x over previous
//
#include <hip/hip_runtime.h>

#define D    300
#define D4   75    // D / 4 float4 chunks
#define KPAD 320   // K padded to 10 MFMA k-steps of 32
#define BM   128
#define BN   64
#define BK   64
#define LDT  72    // LDS row stride in bf16 units (144 B: 16B-aligned, bank-spread)

typedef short bf16x8 __attribute__((ext_vector_type(8)));
typedef float f32x4  __attribute__((ext_vector_type(4)));

__device__ inline short f2bh(float f) {           // fp32 -> bf16 RNE (bit trick)
    unsigned u = __float_as_uint(f);
    unsigned r = (u + 0x7FFFu + ((u >> 16) & 1u)) >> 16;
    return (short)r;
}
__device__ inline float bh2f(short s) {
    return __uint_as_float(((unsigned)(unsigned short)s) << 16);
}

// ---------------- embedding ----------------
__global__ __launch_bounds__(256) void embed_kernel(const int* __restrict__ x,
                                                    const float4* __restrict__ atomT,
                                                    const float4* __restrict__ wordT,
                                                    float4* __restrict__ h, int N) {
    int idx = blockIdx.x * blockDim.x + threadIdx.x;
    if (idx >= N * D4) return;
    int n = idx / D4, c = idx % D4;
    int a = x[n * 2 + 0];
    int w = x[n * 2 + 1];
    float4 va = atomT[(size_t)a * D4 + c];
    float4 vw = wordT[(size_t)w * D4 + c];
    h[idx] = make_float4(va.x + vw.x, va.y + vw.y, va.z + vw.z, va.w + vw.w);
}

// ---------------- W -> transposed, k-padded, split-bf16 pair ----------------
__global__ __launch_bounds__(256) void wprep_kernel(const float* __restrict__ W,
                                                    short* __restrict__ wh, short* __restrict__ wl) {
    int id = blockIdx.x * blockDim.x + threadIdx.x;
    if (id >= D * KPAD) return;
    int n = id / KPAD, k = id % KPAD;
    float v = (k < D) ? W[(size_t)k * D + n] : 0.f;
    short hh = f2bh(v);
    short ll = f2bh(v - bh2f(hh));
    wh[id] = hh; wl[id] = ll;
}

// ---------------- CSR build ----------------
__global__ __launch_bounds__(256) void cnt_kernel(const int* __restrict__ dst, int* __restrict__ cnt, int E) {
    int i = blockIdx.x * blockDim.x + threadIdx.x;
    if (i < E) atomicAdd(&cnt[dst[i]], 1);
}
__global__ __launch_bounds__(256) void dinv_kernel(const int* __restrict__ cnt, float* __restrict__ dinv, int N) {
    int i = blockIdx.x * blockDim.x + threadIdx.x;
    if (i < N) dinv[i] = rsqrtf((float)(cnt[i] + 1));   // +1 self-loop
}
__global__ __launch_bounds__(1024) void scan_kernel(const int* __restrict__ cnt,
                                                    int* __restrict__ off, int* __restrict__ cursor, int N) {
    __shared__ int warp_sums[16];
    __shared__ int chunk_base;
    const int tid = threadIdx.x;
    const int lane = tid & 63;
    const int wid = tid >> 6;
    if (tid == 0) chunk_base = 0;
    __syncthreads();
    for (int base = 0; base < N; base += 1024) {
        int i = base + tid;
        int v = (i < N) ? cnt[i] : 0;
        int s = v;
        #pragma unroll
        for (int d = 1; d < 64; d <<= 1) {
            int t = __shfl_up(s, d, 64);
            if (lane >= d) s += t;
        }
        if (lane == 63) warp_sums[wid] = s;
        __syncthreads();
        if (wid == 0) {
            int ws = (lane < 16) ? warp_sums[lane] : 0;
            #pragma unroll
            for (int d = 1; d < 16; d <<= 1) {
                int t = __shfl_up(ws, d, 64);
                if (lane >= d) ws += t;
            }
            if (lane < 16) warp_sums[lane] = ws;
        }
        __syncthreads();
        int excl = chunk_base + (wid ? warp_sums[wid - 1] : 0) + s - v;
        if (i < N) { off[i] = excl; cursor[i] = excl; }
        int total = warp_sums[15];
        __syncthreads();
        if (tid == 0) chunk_base += total;
        __syncthreads();
    }
    if (tid == 0) off[N] = chunk_base;
}
__global__ __launch_bounds__(256) void fill_kernel(const int* __restrict__ src, const int* __restrict__ dst,
                                                   const float* __restrict__ dinv, int* __restrict__ cursor,
                                                   int* __restrict__ csr_src, float* __restrict__ csr_w, int E) {
    int e = blockIdx.x * blockDim.x + threadIdx.x;
    if (e >= E) return;
    int s = src[e], d = dst[e];
    int slot = atomicAdd(&cursor[d], 1);
    csr_src[slot] = s;
    csr_w[slot] = dinv[s] * dinv[d];
}

// ---------------- GEMM via MFMA, split-bf16: C = A @ W ----------------
__global__ __launch_bounds__(256) void gemm_mfma(const float* __restrict__ A,
                                                 const short* __restrict__ WtH,
                                                 const short* __restrict__ WtL,
                                                 float* __restrict__ C, int M) {
    __shared__ short AsH[BM][LDT], AsL[BM][LDT];
    __shared__ short BsH[BN][LDT], BsL[BN][LDT];

    const int tid = threadIdx.x;
    const int bm = blockIdx.x * BM;
    const int n0 = blockIdx.y * BN;
    const int lane = tid & 63, wid = tid >> 6;
    const int g4 = lane >> 4, l16 = lane & 15;
    const int wr0 = wid * 32;

    f32x4 acc[2][4];
    #pragma unroll
    for (int i = 0; i < 2; ++i)
        #pragma unroll
        for (int j = 0; j < 4; ++j) acc[i][j] = (f32x4)0.0f;

    for (int k0 = 0; k0 < KPAD; k0 += BK) {
        #pragma unroll
        for (int i = 0; i < 8; ++i) {
            int g = tid + i * 256;            // 2048 float4 granules
            int r = g >> 4, k = (g & 15) * 4;
            int gr = bm + r;
            float4 v = make_float4(0.f, 0.f, 0.f, 0.f);
            if (gr < M) {
                int gk = k0 + k;
                if (gk + 3 < D) v = *(const float4*)&A[(size_t)gr * D + gk];
                else {
                    float t0 = (gk + 0 < D) ? A[(size_t)gr * D + gk + 0] : 0.f;
                    float t1 = (gk + 1 < D) ? A[(size_t)gr * D + gk + 1] : 0.f;
                    float t2 = (gk + 2 < D) ? A[(size_t)gr * D + gk + 2] : 0.f;
                    float t3 = (gk + 3 < D) ? A[(size_t)gr * D + gk + 3] : 0.f;
                    v = make_float4(t0, t1, t2, t3);
                }
            }
            short4 hh, ll;
            hh.x = f2bh(v.x); ll.x = f2bh(v.x - bh2f(hh.x));
            hh.y = f2bh(v.y); ll.y = f2bh(v.y - bh2f(hh.y));
            hh.z = f2bh(v.z); ll.z = f2bh(v.z - bh2f(hh.z));
            hh.w = f2bh(v.w); ll.w = f2bh(v.w - bh2f(hh.w));
            *(short4*)&AsH[r][k] = hh;
            *(short4*)&AsL[r][k] = ll;
        }
        #pragma unroll
        for (int i = 0; i < 2; ++i) {
            int g = tid + i * 256;            // 512 chunks of 8 bf16
            int r = g >> 3, k = (g & 7) * 8;
            int gn = n0 + r;
            bf16x8 vh = (bf16x8)(short)0, vl = (bf16x8)(short)0;
            if (gn < D) {
                vh = *(const bf16x8*)&WtH[(size_t)gn * KPAD + k0 + k];
                vl = *(const bf16x8*)&WtL[(size_t)gn * KPAD + k0 + k];
            }
            *(bf16x8*)&BsH[r][k] = vh;
            *(bf16x8*)&BsL[r][k] = vl;
        }
        __syncthreads();

        #pragma unroll
        for (int s = 0; s < 2; ++s) {         // two K=32 steps per BK=64
            bf16x8 ah[2], al[2], bh[4], bl[4];
            #pragma unroll
            for (int mf = 0; mf < 2; ++mf) {
                int row = wr0 + mf * 16 + l16;
                ah[mf] = *(const bf16x8*)&AsH[row][s * 32 + g4 * 8];
                al[mf] = *(const bf16x8*)&AsL[row][s * 32 + g4 * 8];
            }
            #pragma unroll
            for (int nf = 0; nf < 4; ++nf) {
                int col = nf * 16 + l16;
                bh[nf] = *(const bf16x8*)&BsH[col][s * 32 + g4 * 8];
                bl[nf] = *(const bf16x8*)&BsL[col][s * 32 + g4 * 8];
            }
            #pragma unroll
            for (int mf = 0; mf < 2; ++mf)
                #pragma unroll
                for (int nf = 0; nf < 4; ++nf) {
                    acc[mf][nf] = __builtin_amdgcn_mfma_f32_16x16x32_bf16(ah[mf], bh[nf], acc[mf][nf], 0, 0, 0);
                    acc[mf][nf] = __builtin_amdgcn_mfma_f32_16x16x32_bf16(ah[mf], bl[nf], acc[mf][nf], 0, 0, 0);
                    acc[mf][nf] = __builtin_amdgcn_mfma_f32_16x16x32_bf16(al[mf], bh[nf], acc[mf][nf], 0, 0, 0);
                }
        }
        __syncthreads();
    }

    #pragma unroll
    for (int mf = 0; mf < 2; ++mf)
        #pragma unroll
        for (int nf = 0; nf < 4; ++nf)
            #pragma unroll
            for (int reg = 0; reg < 4; ++reg) {
                int grow = bm + wr0 + mf * 16 + g4 * 4 + reg;
                int gcol = n0 + nf * 16 + l16;
                if (grow < M && gcol < D)
                    C[(size_t)grow * D + gcol] = acc[mf][nf][reg];
            }
}

// ---------------- hop aggregate (gather, no atomics) ----------------
__global__ __launch_bounds__(256) void gather_kernel(const float4* __restrict__ hl,
                                                     const int* __restrict__ off,
                                                     const int* __restrict__ csr_src,
                                                     const float* __restrict__ csr_w,
                                                     const float* __restrict__ dinv,
                                                     const float4* __restrict__ bias4,
                                                     float4* __restrict__ h, int N) {
    int idx = blockIdx.x * blockDim.x + threadIdx.x;
    if (idx >= N * D4) return;
    int n = idx / D4, c = idx - n * D4;
    float s = dinv[n]; s = s * s;
    float4 v = hl[idx];
    float4 bb = bias4[c];
    float4 acc = make_float4(bb.x + v.x * s, bb.y + v.y * s, bb.z + v.z * s, bb.w + v.w * s);
    int j0 = off[n], j1 = off[n + 1];
    for (int j = j0; j < j1; ++j) {
        int sn = csr_src[j];
        float w = csr_w[j];
        float4 u = hl[(size_t)sn * D4 + c];
        acc.x += u.x * w; acc.y += u.y * w; acc.z += u.z * w; acc.w += u.w * w;
    }
    h[idx] = acc;
}

// ---------------- pooling via sorted-batch segments (no atomics) ----------------
// start[g] = first node of graph g (batch sorted); start[G] = N.
__global__ __launch_bounds__(256) void seg_start_kernel(const int* __restrict__ batch,
                                                        int* __restrict__ start, int N, int G) {
    int i = blockIdx.x * blockDim.x + threadIdx.x;
    if (i >= N) return;
    int b = batch[i];
    int prev = (i == 0) ? -1 : batch[i - 1];
    for (int g = prev + 1; g <= b; ++g) start[g] = i;      // covers empty graphs
    if (i == N - 1)
        for (int g = b + 1; g <= G; ++g) start[g] = N;
}
__global__ __launch_bounds__(256) void pool_seg(const float* __restrict__ h,
                                                const int* __restrict__ start,
                                                float* __restrict__ out, int G) {
    int g = blockIdx.x;
    if (g >= G) return;
    int j0 = start[g], j1 = start[g + 1];
    float inv = (j1 > j0) ? 1.0f / (float)(j1 - j0) : 0.0f;
    for (int c = threadIdx.x; c < D; c += 256) {
        float acc = 0.f;
        for (int n = j0; n < j1; ++n) acc += h[(size_t)n * D + c];
        out[(size_t)g * D + c] = acc * inv;
    }
}

extern "C" void kernel_launch(void* const* d_in, const int* in_sizes, int n_in,
                              void* d_out, int out_size, void* d_ws, size_t ws_size,
                              hipStream_t stream) {
    (void)n_in; (void)ws_size;
    const int*   x     = (const int*)d_in[0];
    const int*   ei    = (const int*)d_in[1];
    const int*   batch = (const int*)d_in[2];
    // d_in[3] = num_hops (fixed 4)
    const float* atomT = (const float*)d_in[4];
    const float* wordT = (const float*)d_in[5];
    const float* W     = (const float*)d_in[6];
    const float* bias  = (const float*)d_in[7];

    const int N = in_sizes[0] / 2;
    const int E = in_sizes[1] / 2;
    const int G = out_size / D;
    const int NUM_HOPS = 4;

    const int* src = ei;
    const int* dst = ei + E;

    // workspace layout
    float* h       = (float*)d_ws;                    // N*300 f32
    float* hl      = h + (size_t)N * D;               // N*300 f32
    float* dinv    = hl + (size_t)N * D;              // N
    float* csr_w   = dinv + N;                        // E
    short* wtH     = (short*)(csr_w + E);             // 300*KPAD bf16
    short* wtL     = wtH + (size_t)D * KPAD;          // 300*KPAD bf16
    int*   cnt     = (int*)(wtL + (size_t)D * KPAD);  // N
    int*   off     = cnt + N;                         // N+1
    int*   cursor  = off + N + 1;                     // N
    int*   csr_src = cursor + N;                      // E
    int*   start   = csr_src + E;                     // G+1

    const int B = 256;
    int ndBlocks = (N * D4 + B - 1) / B;

    embed_kernel<<<ndBlocks, B, 0, stream>>>(x, (const float4*)atomT, (const float4*)wordT, (float4*)h, N);
    wprep_kernel<<<(D * KPAD + B - 1) / B, B, 0, stream>>>(W, wtH, wtL);

    hipMemsetAsync(cnt, 0, (size_t)N * sizeof(int), stream);
    cnt_kernel <<<(E + B - 1) / B, B, 0, stream>>>(dst, cnt, E);
    dinv_kernel<<<(N + B - 1) / B, B, 0, stream>>>(cnt, dinv, N);
    scan_kernel<<<1, 1024, 0, stream>>>(cnt, off, cursor, N);
    fill_kernel<<<(E + B - 1) / B, B, 0, stream>>>(src, dst, dinv, cursor, csr_src, csr_w, E);
    seg_start_kernel<<<(N + B - 1) / B, B, 0, stream>>>(batch, start, N, G);

    dim3 ggrid((N + BM - 1) / BM, (D + BN - 1) / BN);
    for (int hop = 0; hop < NUM_HOPS; ++hop) {
        gemm_mfma    <<<ggrid, 256, 0, stream>>>(h, wtH, wtL, hl, N);
        gather_kernel<<<ndBlocks, B, 0, stream>>>((const float4*)hl, off, csr_src, csr_w, dinv,
                                                  (const float4*)bias, (float4*)h, N);
    }

    pool_seg<<<G, B, 0, stream>>>(h, start, (float*)d_out, G);
}

// Round 7
// 741.007 us; speedup vs baseline: 8.0872x; 1.1155x over previous
//
#include <hip/hip_runtime.h>

#define D    300
#define D4   75    // D / 4 float4 chunks
#define KPAD 320   // K padded to 10 MFMA k-steps of 32
#define BM   128
#define BN   64
#define BK   32
#define LDT  40    // LDS row stride in bf16 (80 B: 16B-aligned, 20-bank stride)

typedef short bf16x8 __attribute__((ext_vector_type(8)));
typedef float f32x4  __attribute__((ext_vector_type(4)));

__device__ inline short f2bh(float f) {           // fp32 -> bf16 RNE (bit trick)
    unsigned u = __float_as_uint(f);
    unsigned r = (u + 0x7FFFu + ((u >> 16) & 1u)) >> 16;
    return (short)r;
}
__device__ inline float bh2f(short s) {
    return __uint_as_float(((unsigned)(unsigned short)s) << 16);
}

// ---------------- embedding -> split bf16 pair (k-padded layout) ----------------
__global__ __launch_bounds__(256) void embed_kernel(const int* __restrict__ x,
                                                    const float4* __restrict__ atomT,
                                                    const float4* __restrict__ wordT,
                                                    short* __restrict__ hH, short* __restrict__ hL, int N) {
    int idx = blockIdx.x * blockDim.x + threadIdx.x;
    if (idx >= N * D4) return;
    int n = idx / D4, c = idx % D4;
    int a = x[n * 2 + 0];
    int w = x[n * 2 + 1];
    float4 va = atomT[(size_t)a * D4 + c];
    float4 vw = wordT[(size_t)w * D4 + c];
    float4 v = make_float4(va.x + vw.x, va.y + vw.y, va.z + vw.z, va.w + vw.w);
    short4 hh, ll;
    hh.x = f2bh(v.x); ll.x = f2bh(v.x - bh2f(hh.x));
    hh.y = f2bh(v.y); ll.y = f2bh(v.y - bh2f(hh.y));
    hh.z = f2bh(v.z); ll.z = f2bh(v.z - bh2f(hh.z));
    hh.w = f2bh(v.w); ll.w = f2bh(v.w - bh2f(hh.w));
    *(short4*)&hH[(size_t)n * KPAD + c * 4] = hh;
    *(short4*)&hL[(size_t)n * KPAD + c * 4] = ll;
}

// ---------------- W -> transposed, k-padded, split-bf16 pair ----------------
__global__ __launch_bounds__(256) void wprep_kernel(const float* __restrict__ W,
                                                    short* __restrict__ wh, short* __restrict__ wl) {
    int id = blockIdx.x * blockDim.x + threadIdx.x;
    if (id >= D * KPAD) return;
    int n = id / KPAD, k = id % KPAD;
    float v = (k < D) ? W[(size_t)k * D + n] : 0.f;
    short hh = f2bh(v);
    short ll = f2bh(v - bh2f(hh));
    wh[id] = hh; wl[id] = ll;
}

// ---------------- CSR build ----------------
__global__ __launch_bounds__(256) void cnt_kernel(const int* __restrict__ dst, int* __restrict__ cnt, int E) {
    int i = blockIdx.x * blockDim.x + threadIdx.x;
    if (i < E) atomicAdd(&cnt[dst[i]], 1);
}
__global__ __launch_bounds__(256) void dinv_kernel(const int* __restrict__ cnt, float* __restrict__ dinv, int N) {
    int i = blockIdx.x * blockDim.x + threadIdx.x;
    if (i < N) dinv[i] = rsqrtf((float)(cnt[i] + 1));   // +1 self-loop
}
__global__ __launch_bounds__(1024) void scan_kernel(const int* __restrict__ cnt,
                                                    int* __restrict__ off, int* __restrict__ cursor, int N) {
    __shared__ int warp_sums[16];
    __shared__ int chunk_base;
    const int tid = threadIdx.x;
    const int lane = tid & 63;
    const int wid = tid >> 6;
    if (tid == 0) chunk_base = 0;
    __syncthreads();
    for (int base = 0; base < N; base += 1024) {
        int i = base + tid;
        int v = (i < N) ? cnt[i] : 0;
        int s = v;
        #pragma unroll
        for (int d = 1; d < 64; d <<= 1) {
            int t = __shfl_up(s, d, 64);
            if (lane >= d) s += t;
        }
        if (lane == 63) warp_sums[wid] = s;
        __syncthreads();
        if (wid == 0) {
            int ws = (lane < 16) ? warp_sums[lane] : 0;
            #pragma unroll
            for (int d = 1; d < 16; d <<= 1) {
                int t = __shfl_up(ws, d, 64);
                if (lane >= d) ws += t;
            }
            if (lane < 16) warp_sums[lane] = ws;
        }
        __syncthreads();
        int excl = chunk_base + (wid ? warp_sums[wid - 1] : 0) + s - v;
        if (i < N) { off[i] = excl; cursor[i] = excl; }
        int total = warp_sums[15];
        __syncthreads();
        if (tid == 0) chunk_base += total;
        __syncthreads();
    }
    if (tid == 0) off[N] = chunk_base;
}
__global__ __launch_bounds__(256) void fill_kernel(const int* __restrict__ src, const int* __restrict__ dst,
                                                   const float* __restrict__ dinv, int* __restrict__ cursor,
                                                   int* __restrict__ csr_src, float* __restrict__ csr_w, int E) {
    int e = blockIdx.x * blockDim.x + threadIdx.x;
    if (e >= E) return;
    int s = src[e], d = dst[e];
    int slot = atomicAdd(&cursor[d], 1);
    csr_src[slot] = s;
    csr_w[slot] = dinv[s] * dinv[d];
}

// ---------------- GEMM via MFMA, split-bf16 (pre-split A): C = A @ W ----------------
__global__ __launch_bounds__(256) void gemm_mfma(const short* __restrict__ AH,
                                                 const short* __restrict__ AL,
                                                 const short* __restrict__ WtH,
                                                 const short* __restrict__ WtL,
                                                 float* __restrict__ C, int M) {
    __shared__ short AsH[BM][LDT], AsL[BM][LDT];
    __shared__ short BsH[BN][LDT], BsL[BN][LDT];

    const int tid = threadIdx.x;
    const int bm = blockIdx.x * BM;
    const int n0 = blockIdx.y * BN;
    const int lane = tid & 63, wid = tid >> 6;
    const int g4 = lane >> 4, l16 = lane & 15;
    const int wr0 = wid * 32;

    f32x4 acc[2][4];
    #pragma unroll
    for (int i = 0; i < 2; ++i)
        #pragma unroll
        for (int j = 0; j < 4; ++j) acc[i][j] = (f32x4)0.0f;

    for (int k0 = 0; k0 < KPAD; k0 += BK) {
        // ---- stage A: 128x32 bf16 pair, pure 16B copies (2 chunks/thread each) ----
        #pragma unroll
        for (int i = 0; i < 2; ++i) {
            int g = tid + i * 256;            // 512 chunks of 8 bf16
            int r = g >> 2, kc = (g & 3) * 8;
            int gr = bm + r;
            bf16x8 vh = (bf16x8)(short)0, vl = (bf16x8)(short)0;
            if (gr < M) {
                vh = *(const bf16x8*)&AH[(size_t)gr * KPAD + k0 + kc];
                vl = *(const bf16x8*)&AL[(size_t)gr * KPAD + k0 + kc];
            }
            *(bf16x8*)&AsH[r][kc] = vh;
            *(bf16x8*)&AsL[r][kc] = vl;
        }
        // ---- stage B: 64x32 bf16 pair (1 chunk/thread each) ----
        {
            int g = tid;                       // 256 chunks
            int r = g >> 2, kc = (g & 3) * 8;
            int gn = n0 + r;
            bf16x8 vh = (bf16x8)(short)0, vl = (bf16x8)(short)0;
            if (gn < D) {
                vh = *(const bf16x8*)&WtH[(size_t)gn * KPAD + k0 + kc];
                vl = *(const bf16x8*)&WtL[(size_t)gn * KPAD + k0 + kc];
            }
            *(bf16x8*)&BsH[r][kc] = vh;
            *(bf16x8*)&BsL[r][kc] = vl;
        }
        __syncthreads();

        bf16x8 ah[2], al[2], bh[4], bl[4];
        #pragma unroll
        for (int mf = 0; mf < 2; ++mf) {
            int row = wr0 + mf * 16 + l16;
            ah[mf] = *(const bf16x8*)&AsH[row][g4 * 8];
            al[mf] = *(const bf16x8*)&AsL[row][g4 * 8];
        }
        #pragma unroll
        for (int nf = 0; nf < 4; ++nf) {
            int col = nf * 16 + l16;
            bh[nf] = *(const bf16x8*)&BsH[col][g4 * 8];
            bl[nf] = *(const bf16x8*)&BsL[col][g4 * 8];
        }
        #pragma unroll
        for (int mf = 0; mf < 2; ++mf)
            #pragma unroll
            for (int nf = 0; nf < 4; ++nf) {
                acc[mf][nf] = __builtin_amdgcn_mfma_f32_16x16x32_bf16(ah[mf], bh[nf], acc[mf][nf], 0, 0, 0);
                acc[mf][nf] = __builtin_amdgcn_mfma_f32_16x16x32_bf16(ah[mf], bl[nf], acc[mf][nf], 0, 0, 0);
                acc[mf][nf] = __builtin_amdgcn_mfma_f32_16x16x32_bf16(al[mf], bh[nf], acc[mf][nf], 0, 0, 0);
            }
        __syncthreads();
    }

    // ---- C write: row=(lane>>4)*4+reg, col=lane&15 per 16x16 frag ----
    #pragma unroll
    for (int mf = 0; mf < 2; ++mf)
        #pragma unroll
        for (int nf = 0; nf < 4; ++nf)
            #pragma unroll
            for (int reg = 0; reg < 4; ++reg) {
                int grow = bm + wr0 + mf * 16 + g4 * 4 + reg;
                int gcol = n0 + nf * 16 + l16;
                if (grow < M && gcol < D)
                    C[(size_t)grow * D + gcol] = acc[mf][nf][reg];
            }
}

// ---------------- hop aggregate (gather) -> split bf16 pair ----------------
__global__ __launch_bounds__(256) void gather_kernel(const float4* __restrict__ hl,
                                                     const int* __restrict__ off,
                                                     const int* __restrict__ csr_src,
                                                     const float* __restrict__ csr_w,
                                                     const float* __restrict__ dinv,
                                                     const float4* __restrict__ bias4,
                                                     short* __restrict__ hH, short* __restrict__ hL, int N) {
    int idx = blockIdx.x * blockDim.x + threadIdx.x;
    if (idx >= N * D4) return;
    int n = idx / D4, c = idx - n * D4;
    float s = dinv[n]; s = s * s;
    float4 v = hl[idx];
    float4 bb = bias4[c];
    float4 acc = make_float4(bb.x + v.x * s, bb.y + v.y * s, bb.z + v.z * s, bb.w + v.w * s);
    int j0 = off[n], j1 = off[n + 1];
    for (int j = j0; j < j1; ++j) {
        int sn = csr_src[j];
        float w = csr_w[j];
        float4 u = hl[(size_t)sn * D4 + c];
        acc.x += u.x * w; acc.y += u.y * w; acc.z += u.z * w; acc.w += u.w * w;
    }
    short4 hh, ll;
    hh.x = f2bh(acc.x); ll.x = f2bh(acc.x - bh2f(hh.x));
    hh.y = f2bh(acc.y); ll.y = f2bh(acc.y - bh2f(hh.y));
    hh.z = f2bh(acc.z); ll.z = f2bh(acc.z - bh2f(hh.z));
    hh.w = f2bh(acc.w); ll.w = f2bh(acc.w - bh2f(hh.w));
    *(short4*)&hH[(size_t)n * KPAD + c * 4] = hh;
    *(short4*)&hL[(size_t)n * KPAD + c * 4] = ll;
}

// ---------------- pooling via sorted-batch segments ----------------
__global__ __launch_bounds__(256) void seg_start_kernel(const int* __restrict__ batch,
                                                        int* __restrict__ start, int N, int G) {
    int i = blockIdx.x * blockDim.x + threadIdx.x;
    if (i >= N) return;
    int b = batch[i];
    int prev = (i == 0) ? -1 : batch[i - 1];
    for (int g = prev + 1; g <= b; ++g) start[g] = i;
    if (i == N - 1)
        for (int g = b + 1; g <= G; ++g) start[g] = N;
}
__global__ __launch_bounds__(256) void pool_seg(const short* __restrict__ hH,
                                                const short* __restrict__ hL,
                                                const int* __restrict__ start,
                                                float* __restrict__ out, int G) {
    int g = blockIdx.x;
    if (g >= G) return;
    int j0 = start[g], j1 = start[g + 1];
    float inv = (j1 > j0) ? 1.0f / (float)(j1 - j0) : 0.0f;
    for (int c = threadIdx.x; c < D; c += 256) {
        float acc = 0.f;
        for (int n = j0; n < j1; ++n)
            acc += bh2f(hH[(size_t)n * KPAD + c]) + bh2f(hL[(size_t)n * KPAD + c]);
        out[(size_t)g * D + c] = acc * inv;
    }
}

extern "C" void kernel_launch(void* const* d_in, const int* in_sizes, int n_in,
                              void* d_out, int out_size, void* d_ws, size_t ws_size,
                              hipStream_t stream) {
    (void)n_in; (void)ws_size;
    const int*   x     = (const int*)d_in[0];
    const int*   ei    = (const int*)d_in[1];
    const int*   batch = (const int*)d_in[2];
    // d_in[3] = num_hops (fixed 4)
    const float* atomT = (const float*)d_in[4];
    const float* wordT = (const float*)d_in[5];
    const float* W     = (const float*)d_in[6];
    const float* bias  = (const float*)d_in[7];

    const int N = in_sizes[0] / 2;
    const int E = in_sizes[1] / 2;
    const int G = out_size / D;
    const int NUM_HOPS = 4;

    const int* src = ei;
    const int* dst = ei + E;

    // workspace layout (all segment starts 16B-aligned)
    float* hl      = (float*)d_ws;                    // N*D f32
    float* dinv    = hl + (size_t)N * D;              // N
    float* csr_w   = dinv + N;                        // E
    short* wtH     = (short*)(csr_w + E);             // D*KPAD bf16
    short* wtL     = wtH + (size_t)D * KPAD;          // D*KPAD bf16
    short* hH      = wtL + (size_t)D * KPAD;          // N*KPAD bf16
    short* hLo     = hH + (size_t)N * KPAD;           // N*KPAD bf16
    int*   cnt     = (int*)(hLo + (size_t)N * KPAD);  // N
    int*   off     = cnt + N;                         // N+1
    int*   cursor  = off + N + 1;                     // N
    int*   csr_src = cursor + N;                      // E
    int*   start   = csr_src + E;                     // G+1

    const int B = 256;
    int ndBlocks = (N * D4 + B - 1) / B;

    // zero the k-pad columns (embed/gather only write c<300)
    hipMemsetAsync(hH, 0, (size_t)N * KPAD * sizeof(short), stream);
    hipMemsetAsync(hLo, 0, (size_t)N * KPAD * sizeof(short), stream);

    embed_kernel<<<ndBlocks, B, 0, stream>>>(x, (const float4*)atomT, (const float4*)wordT, hH, hLo, N);
    wprep_kernel<<<(D * KPAD + B - 1) / B, B, 0, stream>>>(W, wtH, wtL);

    hipMemsetAsync(cnt, 0, (size_t)N * sizeof(int), stream);
    cnt_kernel <<<(E + B - 1) / B, B, 0, stream>>>(dst, cnt, E);
    dinv_kernel<<<(N + B - 1) / B, B, 0, stream>>>(cnt, dinv, N);
    scan_kernel<<<1, 1024, 0, stream>>>(cnt, off, cursor, N);
    fill_kernel<<<(E + B - 1) / B, B, 0, stream>>>(src, dst, dinv, cursor, csr_src, csr_w, E);
    seg_start_kernel<<<(N + B - 1) / B, B, 0, stream>>>(batch, start, N, G);

    dim3 ggrid((N + BM - 1) / BM, (D + BN - 1) / BN);
    for (int hop = 0; hop < NUM_HOPS; ++hop) {
        gemm_mfma    <<<ggrid, 256, 0, stream>>>(hH, hLo, wtH, wtL, hl, N);
        gather_kernel<<<ndBlocks, B, 0, stream>>>((const float4*)hl, off, csr_src, csr_w, dinv,
                                                  (const float4*)bias, hH, hLo, N);
    }

    pool_seg<<<G, B, 0, stream>>>(hH, hLo, start, (float*)d_out, G);
}

// Round 8
// 620.553 us; speedup vs baseline: 9.6570x; 1.1941x over previous
//
#include <hip/hip_runtime.h>

#define D    300
#define D4   75    // D / 4 float4 chunks
#define KPAD 320   // K padded to 10 MFMA k-steps of 32
#define BM   128
#define BN   64
#define BK   32
#define LDT  40    // LDS row stride in bf16 (80 B: 16B-aligned, 20-bank stride)
#define NNB  5     // n-blocks per m-panel (ceil(300/64))

typedef short bf16x8 __attribute__((ext_vector_type(8)));
typedef float f32x4  __attribute__((ext_vector_type(4)));

__device__ inline short f2bh(float f) {           // fp32 -> bf16 RNE (bit trick)
    unsigned u = __float_as_uint(f);
    unsigned r = (u + 0x7FFFu + ((u >> 16) & 1u)) >> 16;
    return (short)r;
}
__device__ inline float bh2f(short s) {
    return __uint_as_float(((unsigned)(unsigned short)s) << 16);
}

// ---------------- embedding -> split bf16 pair (k-padded layout) ----------------
__global__ __launch_bounds__(256) void embed_kernel(const int* __restrict__ x,
                                                    const float4* __restrict__ atomT,
                                                    const float4* __restrict__ wordT,
                                                    short* __restrict__ hH, short* __restrict__ hL, int N) {
    int idx = blockIdx.x * blockDim.x + threadIdx.x;
    if (idx >= N * D4) return;
    int n = idx / D4, c = idx % D4;
    int a = x[n * 2 + 0];
    int w = x[n * 2 + 1];
    float4 va = atomT[(size_t)a * D4 + c];
    float4 vw = wordT[(size_t)w * D4 + c];
    float4 v = make_float4(va.x + vw.x, va.y + vw.y, va.z + vw.z, va.w + vw.w);
    short4 hh, ll;
    hh.x = f2bh(v.x); ll.x = f2bh(v.x - bh2f(hh.x));
    hh.y = f2bh(v.y); ll.y = f2bh(v.y - bh2f(hh.y));
    hh.z = f2bh(v.z); ll.z = f2bh(v.z - bh2f(hh.z));
    hh.w = f2bh(v.w); ll.w = f2bh(v.w - bh2f(hh.w));
    *(short4*)&hH[(size_t)n * KPAD + c * 4] = hh;
    *(short4*)&hL[(size_t)n * KPAD + c * 4] = ll;
}

// ---------------- W -> transposed, k-padded, split-bf16 pair ----------------
__global__ __launch_bounds__(256) void wprep_kernel(const float* __restrict__ W,
                                                    short* __restrict__ wh, short* __restrict__ wl) {
    int id = blockIdx.x * blockDim.x + threadIdx.x;
    if (id >= D * KPAD) return;
    int n = id / KPAD, k = id % KPAD;
    float v = (k < D) ? W[(size_t)k * D + n] : 0.f;
    short hh = f2bh(v);
    short ll = f2bh(v - bh2f(hh));
    wh[id] = hh; wl[id] = ll;
}

// ---------------- CSR build ----------------
__global__ __launch_bounds__(256) void cnt_kernel(const int* __restrict__ dst, int* __restrict__ cnt, int E) {
    int i = blockIdx.x * blockDim.x + threadIdx.x;
    if (i < E) atomicAdd(&cnt[dst[i]], 1);
}
__global__ __launch_bounds__(256) void dinv_kernel(const int* __restrict__ cnt, float* __restrict__ dinv, int N) {
    int i = blockIdx.x * blockDim.x + threadIdx.x;
    if (i < N) dinv[i] = rsqrtf((float)(cnt[i] + 1));   // +1 self-loop
}
__global__ __launch_bounds__(1024) void scan_kernel(const int* __restrict__ cnt,
                                                    int* __restrict__ off, int* __restrict__ cursor, int N) {
    __shared__ int warp_sums[16];
    __shared__ int chunk_base;
    const int tid = threadIdx.x;
    const int lane = tid & 63;
    const int wid = tid >> 6;
    if (tid == 0) chunk_base = 0;
    __syncthreads();
    for (int base = 0; base < N; base += 1024) {
        int i = base + tid;
        int v = (i < N) ? cnt[i] : 0;
        int s = v;
        #pragma unroll
        for (int d = 1; d < 64; d <<= 1) {
            int t = __shfl_up(s, d, 64);
            if (lane >= d) s += t;
        }
        if (lane == 63) warp_sums[wid] = s;
        __syncthreads();
        if (wid == 0) {
            int ws = (lane < 16) ? warp_sums[lane] : 0;
            #pragma unroll
            for (int d = 1; d < 16; d <<= 1) {
                int t = __shfl_up(ws, d, 64);
                if (lane >= d) ws += t;
            }
            if (lane < 16) warp_sums[lane] = ws;
        }
        __syncthreads();
        int excl = chunk_base + (wid ? warp_sums[wid - 1] : 0) + s - v;
        if (i < N) { off[i] = excl; cursor[i] = excl; }
        int total = warp_sums[15];
        __syncthreads();
        if (tid == 0) chunk_base += total;
        __syncthreads();
    }
    if (tid == 0) off[N] = chunk_base;
}
__global__ __launch_bounds__(256) void fill_kernel(const int* __restrict__ src, const int* __restrict__ dst,
                                                   const float* __restrict__ dinv, int* __restrict__ cursor,
                                                   int* __restrict__ csr_src, float* __restrict__ csr_w, int E) {
    int e = blockIdx.x * blockDim.x + threadIdx.x;
    if (e >= E) return;
    int s = src[e], d = dst[e];
    int slot = atomicAdd(&cursor[d], 1);
    csr_src[slot] = s;
    csr_w[slot] = dinv[s] * dinv[d];
}

// ---------------- GEMM via MFMA, split-bf16 (pre-split A): C = A @ W ----------------
// 1D grid, XCD-swizzled: d = q*(8*NNB) + nb*8 + r, mb = q*8 + r.
// All NNB n-blocks of an m-panel share d%8 -> same XCD (round-robin heuristic)
// -> A panel fetched once into that XCD's L2. Correctness independent of mapping.
__global__ __launch_bounds__(256) void gemm_mfma(const short* __restrict__ AH,
                                                 const short* __restrict__ AL,
                                                 const short* __restrict__ WtH,
                                                 const short* __restrict__ WtL,
                                                 float* __restrict__ C, int M) {
    const int d_lin = blockIdx.x;
    const int q   = d_lin / (8 * NNB);
    const int rem = d_lin % (8 * NNB);
    const int nb  = rem >> 3;
    const int r   = rem & 7;
    const int mb  = q * 8 + r;
    if (mb * BM >= M) return;
    const int bm = mb * BM;
    const int n0 = nb * BN;

    __shared__ short AsH[BM][LDT], AsL[BM][LDT];
    __shared__ short BsH[BN][LDT], BsL[BN][LDT];

    const int tid = threadIdx.x;
    const int lane = tid & 63, wid = tid >> 6;
    const int g4 = lane >> 4, l16 = lane & 15;
    const int wr0 = wid * 32;

    f32x4 acc[2][4];
    #pragma unroll
    for (int i = 0; i < 2; ++i)
        #pragma unroll
        for (int j = 0; j < 4; ++j) acc[i][j] = (f32x4)0.0f;

    for (int k0 = 0; k0 < KPAD; k0 += BK) {
        // ---- stage A: 128x32 bf16 pair, pure 16B copies ----
        #pragma unroll
        for (int i = 0; i < 2; ++i) {
            int g = tid + i * 256;            // 512 chunks of 8 bf16
            int rr = g >> 2, kc = (g & 3) * 8;
            int gr = bm + rr;
            bf16x8 vh = (bf16x8)(short)0, vl = (bf16x8)(short)0;
            if (gr < M) {
                vh = *(const bf16x8*)&AH[(size_t)gr * KPAD + k0 + kc];
                vl = *(const bf16x8*)&AL[(size_t)gr * KPAD + k0 + kc];
            }
            *(bf16x8*)&AsH[rr][kc] = vh;
            *(bf16x8*)&AsL[rr][kc] = vl;
        }
        // ---- stage B: 64x32 bf16 pair ----
        {
            int g = tid;                       // 256 chunks
            int rr = g >> 2, kc = (g & 3) * 8;
            int gn = n0 + rr;
            bf16x8 vh = (bf16x8)(short)0, vl = (bf16x8)(short)0;
            if (gn < D) {
                vh = *(const bf16x8*)&WtH[(size_t)gn * KPAD + k0 + kc];
                vl = *(const bf16x8*)&WtL[(size_t)gn * KPAD + k0 + kc];
            }
            *(bf16x8*)&BsH[rr][kc] = vh;
            *(bf16x8*)&BsL[rr][kc] = vl;
        }
        __syncthreads();

        bf16x8 ah[2], al[2], bh[4], bl[4];
        #pragma unroll
        for (int mf = 0; mf < 2; ++mf) {
            int row = wr0 + mf * 16 + l16;
            ah[mf] = *(const bf16x8*)&AsH[row][g4 * 8];
            al[mf] = *(const bf16x8*)&AsL[row][g4 * 8];
        }
        #pragma unroll
        for (int nf = 0; nf < 4; ++nf) {
            int col = nf * 16 + l16;
            bh[nf] = *(const bf16x8*)&BsH[col][g4 * 8];
            bl[nf] = *(const bf16x8*)&BsL[col][g4 * 8];
        }
        #pragma unroll
        for (int mf = 0; mf < 2; ++mf)
            #pragma unroll
            for (int nf = 0; nf < 4; ++nf) {
                acc[mf][nf] = __builtin_amdgcn_mfma_f32_16x16x32_bf16(ah[mf], bh[nf], acc[mf][nf], 0, 0, 0);
                acc[mf][nf] = __builtin_amdgcn_mfma_f32_16x16x32_bf16(ah[mf], bl[nf], acc[mf][nf], 0, 0, 0);
                acc[mf][nf] = __builtin_amdgcn_mfma_f32_16x16x32_bf16(al[mf], bh[nf], acc[mf][nf], 0, 0, 0);
            }
        __syncthreads();
    }

    // ---- C write: row=(lane>>4)*4+reg, col=lane&15 per 16x16 frag ----
    #pragma unroll
    for (int mf = 0; mf < 2; ++mf)
        #pragma unroll
        for (int nf = 0; nf < 4; ++nf)
            #pragma unroll
            for (int reg = 0; reg < 4; ++reg) {
                int grow = bm + wr0 + mf * 16 + g4 * 4 + reg;
                int gcol = n0 + nf * 16 + l16;
                if (grow < M && gcol < D)
                    C[(size_t)grow * D + gcol] = acc[mf][nf][reg];
            }
}

// ---------------- hop aggregate (gather) -> split bf16 pair ----------------
__global__ __launch_bounds__(256) void gather_kernel(const float4* __restrict__ hl,
                                                     const int* __restrict__ off,
                                                     const int* __restrict__ csr_src,
                                                     const float* __restrict__ csr_w,
                                                     const float* __restrict__ dinv,
                                                     const float4* __restrict__ bias4,
                                                     short* __restrict__ hH, short* __restrict__ hL, int N) {
    int idx = blockIdx.x * blockDim.x + threadIdx.x;
    if (idx >= N * D4) return;
    int n = idx / D4, c = idx - n * D4;
    float s = dinv[n]; s = s * s;
    float4 v = hl[idx];
    float4 bb = bias4[c];
    float4 acc = make_float4(bb.x + v.x * s, bb.y + v.y * s, bb.z + v.z * s, bb.w + v.w * s);
    int j0 = off[n], j1 = off[n + 1];
    for (int j = j0; j < j1; ++j) {
        int sn = csr_src[j];
        float w = csr_w[j];
        float4 u = hl[(size_t)sn * D4 + c];
        acc.x += u.x * w; acc.y += u.y * w; acc.z += u.z * w; acc.w += u.w * w;
    }
    short4 hh, ll;
    hh.x = f2bh(acc.x); ll.x = f2bh(acc.x - bh2f(hh.x));
    hh.y = f2bh(acc.y); ll.y = f2bh(acc.y - bh2f(hh.y));
    hh.z = f2bh(acc.z); ll.z = f2bh(acc.z - bh2f(hh.z));
    hh.w = f2bh(acc.w); ll.w = f2bh(acc.w - bh2f(hh.w));
    *(short4*)&hH[(size_t)n * KPAD + c * 4] = hh;
    *(short4*)&hL[(size_t)n * KPAD + c * 4] = ll;
}

// ---------------- pooling via sorted-batch segments ----------------
__global__ __launch_bounds__(256) void seg_start_kernel(const int* __restrict__ batch,
                                                        int* __restrict__ start, int N, int G) {
    int i = blockIdx.x * blockDim.x + threadIdx.x;
    if (i >= N) return;
    int b = batch[i];
    int prev = (i == 0) ? -1 : batch[i - 1];
    for (int g = prev + 1; g <= b; ++g) start[g] = i;
    if (i == N - 1)
        for (int g = b + 1; g <= G; ++g) start[g] = N;
}
__global__ __launch_bounds__(256) void pool_seg(const short* __restrict__ hH,
                                                const short* __restrict__ hL,
                                                const int* __restrict__ start,
                                                float* __restrict__ out, int G) {
    int g = blockIdx.x;
    if (g >= G) return;
    int j0 = start[g], j1 = start[g + 1];
    float inv = (j1 > j0) ? 1.0f / (float)(j1 - j0) : 0.0f;
    for (int c = threadIdx.x; c < D; c += 256) {
        float acc = 0.f;
        for (int n = j0; n < j1; ++n)
            acc += bh2f(hH[(size_t)n * KPAD + c]) + bh2f(hL[(size_t)n * KPAD + c]);
        out[(size_t)g * D + c] = acc * inv;
    }
}

extern "C" void kernel_launch(void* const* d_in, const int* in_sizes, int n_in,
                              void* d_out, int out_size, void* d_ws, size_t ws_size,
                              hipStream_t stream) {
    (void)n_in; (void)ws_size;
    const int*   x     = (const int*)d_in[0];
    const int*   ei    = (const int*)d_in[1];
    const int*   batch = (const int*)d_in[2];
    // d_in[3] = num_hops (fixed 4)
    const float* atomT = (const float*)d_in[4];
    const float* wordT = (const float*)d_in[5];
    const float* W     = (const float*)d_in[6];
    const float* bias  = (const float*)d_in[7];

    const int N = in_sizes[0] / 2;
    const int E = in_sizes[1] / 2;
    const int G = out_size / D;
    const int NUM_HOPS = 4;

    const int* src = ei;
    const int* dst = ei + E;

    // workspace layout (all segment starts 16B-aligned)
    float* hl      = (float*)d_ws;                    // N*D f32
    float* dinv    = hl + (size_t)N * D;              // N
    float* csr_w   = dinv + N;                        // E
    short* wtH     = (short*)(csr_w + E);             // D*KPAD bf16
    short* wtL     = wtH + (size_t)D * KPAD;          // D*KPAD bf16
    short* hH      = wtL + (size_t)D * KPAD;          // N*KPAD bf16
    short* hLo     = hH + (size_t)N * KPAD;           // N*KPAD bf16
    int*   cnt     = (int*)(hLo + (size_t)N * KPAD);  // N
    int*   off     = cnt + N;                         // N+1
    int*   cursor  = off + N + 1;                     // N
    int*   csr_src = cursor + N;                      // E
    int*   start   = csr_src + E;                     // G+1

    const int B = 256;
    int ndBlocks = (N * D4 + B - 1) / B;

    // zero the k-pad columns (embed/gather only write c<300)
    hipMemsetAsync(hH, 0, (size_t)N * KPAD * sizeof(short), stream);
    hipMemsetAsync(hLo, 0, (size_t)N * KPAD * sizeof(short), stream);

    embed_kernel<<<ndBlocks, B, 0, stream>>>(x, (const float4*)atomT, (const float4*)wordT, hH, hLo, N);
    wprep_kernel<<<(D * KPAD + B - 1) / B, B, 0, stream>>>(W, wtH, wtL);

    hipMemsetAsync(cnt, 0, (size_t)N * sizeof(int), stream);
    cnt_kernel <<<(E + B - 1) / B, B, 0, stream>>>(dst, cnt, E);
    dinv_kernel<<<(N + B - 1) / B, B, 0, stream>>>(cnt, dinv, N);
    scan_kernel<<<1, 1024, 0, stream>>>(cnt, off, cursor, N);
    fill_kernel<<<(E + B - 1) / B, B, 0, stream>>>(src, dst, dinv, cursor, csr_src, csr_w, E);
    seg_start_kernel<<<(N + B - 1) / B, B, 0, stream>>>(batch, start, N, G);

    // XCD-swizzled 1D grid: ceil(nm/8) groups x 8 m-slots x NNB n-blocks
    const int nmB = (N + BM - 1) / BM;
    const int gemmBlocks = ((nmB + 7) / 8) * 8 * NNB;
    for (int hop = 0; hop < NUM_HOPS; ++hop) {
        gemm_mfma    <<<gemmBlocks, 256, 0, stream>>>(hH, hLo, wtH, wtL, hl, N);
        gather_kernel<<<ndBlocks, B, 0, stream>>>((const float4*)hl, off, csr_src, csr_w, dinv,
                                                  (const float4*)bias, hH, hLo, N);
    }

    pool_seg<<<G, B, 0, stream>>>(hH, hLo, start, (float*)d_out, G);
}